// Round 4
// baseline (194.226 us; speedup 1.0000x reference)
//
#include <hip/hip_runtime.h>
#include <math.h>

// LayerSumSimple: K-level chained cummax-of-sums == max-plus affine scan with
// 8-element state s:  s[k] <- max(s[k], s[k-1] + g_k(t)),  g_k = x*w[k]+b[k].
// 3 launches:
//   pass1: per-chunk max-plus affine summary (28 strict-lower A + 8 c)
//   pass2: ONE fused kernel: serial apply over all C chunk maps per (b,d),
//          ring-of-3 register prefetch -> per-chunk inflow states
//   pass3: re-scan each chunk from true inflow (float2/thread), emit outputs
namespace {
constexpr int BB   = 8;
constexpr int TT   = 8192;
constexpr int DD   = 256;
constexpr int KK   = 8;
constexpr int TOUT = TT - KK + 1;       // 8185
constexpr int NSUM = 36;                // 8 c-vector + 28 strict-lower A
constexpr int C    = 128;               // chunks per sequence (compile-time)
constexpr int L    = TT / C;            // 64 steps per chunk

__host__ __device__ __forceinline__ constexpr int tri(int k, int j) {
    return 8 + k * (k - 1) / 2 + j;     // k in [1,8), j < k  (max = 35)
}

// one time-step of the summary recurrence (descending k uses OLD row k-1)
__device__ __forceinline__ void step_sum(float x, const float (&wk)[KK],
                                         const float (&bk)[KK],
                                         float (&A)[KK][KK], float (&cv)[KK])
{
    float g[KK];
    #pragma unroll
    for (int k = 0; k < KK; ++k) g[k] = fmaf(x, wk[k], bk[k]);
    #pragma unroll
    for (int k = KK - 1; k >= 1; --k) {
        #pragma unroll
        for (int j = 0; j < k - 1; ++j)
            A[k][j] = fmaxf(A[k][j], g[k] + A[k - 1][j]);
        A[k][k - 1] = fmaxf(A[k][k - 1], g[k]);  // A[k-1][k-1] == 0 (diag)
        cv[k] = fmaxf(cv[k], g[k] + cv[k - 1]);
    }
    cv[0] = fmaxf(cv[0], g[0]);
}

// ---- pass 1: one block per (b, chunk); thread d = channel; 8-deep pipeline ----
constexpr int U1 = 8;
__global__ __launch_bounds__(256) void pass1_summaries(
    const float* __restrict__ X, const float* __restrict__ W,
    const float* __restrict__ Bv, float* __restrict__ sum)
{
    const int b = blockIdx.x / C;
    const int c = blockIdx.x % C;
    const int d = threadIdx.x;

    float wk[KK], bk[KK];
    #pragma unroll
    for (int k = 0; k < KK; ++k) { wk[k] = W[k * DD + d]; bk[k] = Bv[k * DD + d]; }

    float cv[KK];
    float A[KK][KK];
    #pragma unroll
    for (int k = 0; k < KK; ++k) {
        cv[k] = -INFINITY;
        #pragma unroll
        for (int j = 0; j < KK; ++j) A[k][j] = -INFINITY;
    }

    const float* xp = X + (b * TT + c * L) * DD + d;   // all indices < 2^31
    constexpr int nb = L / U1;                          // 8
    float x0[U1], x1[U1];
    #pragma unroll
    for (int u = 0; u < U1; ++u) x0[u] = xp[u * DD];

    #pragma unroll
    for (int ib = 0; ib < nb; ib += 2) {
        const float* p1 = xp + (ib + 1) * U1 * DD;
        #pragma unroll
        for (int u = 0; u < U1; ++u) x1[u] = p1[u * DD];
        #pragma unroll
        for (int u = 0; u < U1; ++u) step_sum(x0[u], wk, bk, A, cv);
        if (ib + 2 < nb) {
            const float* p2 = xp + (ib + 2) * U1 * DD;
            #pragma unroll
            for (int u = 0; u < U1; ++u) x0[u] = p2[u * DD];
        }
        #pragma unroll
        for (int u = 0; u < U1; ++u) step_sum(x1[u], wk, bk, A, cv);
    }

    float* sp = sum + (b * C + c) * NSUM * DD + d;
    #pragma unroll
    for (int k = 0; k < KK; ++k) sp[k * DD] = cv[k];
    #pragma unroll
    for (int k = 1; k < KK; ++k) {
        #pragma unroll
        for (int j = 0; j < k; ++j) sp[tri(k, j) * DD] = A[k][j];
    }
}

// ---- pass 2: ONE kernel. 32 blocks x 64 thr; block = (b, 64-channel group).
// Serial apply over C chunk maps with ring-of-3 register prefetch. ----
__global__ __launch_bounds__(64) void pass2_inflows(
    const float* __restrict__ sum, float* __restrict__ infl)
{
    const int b  = blockIdx.x >> 2;
    const int dg = blockIdx.x & 3;
    const int d  = dg * 64 + threadIdx.x;

    const float* base = sum + b * C * NSUM * DD + d;
    float* ibase = infl + b * C * KK * DD + d;

    float s[KK];
    #pragma unroll
    for (int k = 0; k < KK; ++k) s[k] = -INFINITY;

    float m0[NSUM], m1[NSUM], m2[NSUM];

    auto LD = [&](float (&m)[NSUM], int c) {
        const float* sp = base + c * NSUM * DD;
        #pragma unroll
        for (int i = 0; i < NSUM; ++i) m[i] = sp[i * DD];
    };
    auto AP = [&](const float (&m)[NSUM], int c) {
        float* ip = ibase + c * KK * DD;
        #pragma unroll
        for (int k = 0; k < KK; ++k) ip[k * DD] = s[k];  // inflow BEFORE chunk c
        float ns[KK];
        #pragma unroll
        for (int k = 0; k < KK; ++k) ns[k] = fmaxf(m[k], s[k]);  // c[k], diag
        #pragma unroll
        for (int k = 1; k < KK; ++k) {
            #pragma unroll
            for (int j = 0; j < k; ++j)
                ns[k] = fmaxf(ns[k], m[tri(k, j)] + s[j]);
        }
        #pragma unroll
        for (int k = 0; k < KK; ++k) s[k] = ns[k];
    };

    LD(m0, 0); LD(m1, 1); LD(m2, 2);
    int c = 0;
    for (; c + 5 < C; c += 3) {
        AP(m0, c);     LD(m0, c + 3);
        AP(m1, c + 1); LD(m1, c + 4);
        AP(m2, c + 2); LD(m2, c + 5);
    }
    // C=128: loop exits at c=123 with m0=123, m1=124, m2=125 loaded.
    AP(m0, c);     LD(m0, c + 3);
    AP(m1, c + 1); LD(m1, c + 4);
    AP(m2, c + 2);
    AP(m0, c + 3);
    AP(m1, c + 4);
}

// ---- pass 3: one block (128 thr) per (b, chunk); float2/thread scan ----
__device__ __forceinline__ void step_scan2(float2 x, const float2 (&wk)[KK],
                                           const float2 (&bk)[KK], float2 (&s)[KK])
{
    float2 g[KK];
    #pragma unroll
    for (int k = 0; k < KK; ++k) {
        g[k].x = fmaf(x.x, wk[k].x, bk[k].x);
        g[k].y = fmaf(x.y, wk[k].y, bk[k].y);
    }
    #pragma unroll
    for (int k = KK - 1; k >= 1; --k) {
        s[k].x = fmaxf(s[k].x, s[k - 1].x + g[k].x);
        s[k].y = fmaxf(s[k].y, s[k - 1].y + g[k].y);
    }
    s[0].x = fmaxf(s[0].x, g[0].x);
    s[0].y = fmaxf(s[0].y, g[0].y);
}

constexpr int U3 = 8;
__global__ __launch_bounds__(128) void pass3_scan(
    const float* __restrict__ X, const float* __restrict__ W,
    const float* __restrict__ Bv, const float* __restrict__ infl,
    float* __restrict__ out)
{
    const int b = blockIdx.x / C;
    const int c = blockIdx.x % C;
    const int d = threadIdx.x;              // channel pair: 2d, 2d+1

    const float2* W2 = (const float2*)W;
    const float2* B2 = (const float2*)Bv;
    float2 wk[KK], bk[KK];
    #pragma unroll
    for (int k = 0; k < KK; ++k) { wk[k] = W2[k * (DD/2) + d]; bk[k] = B2[k * (DD/2) + d]; }

    float2 s[KK];
    const float* ip = infl + (b * C + c) * KK * DD + 2 * d;
    #pragma unroll
    for (int k = 0; k < KK; ++k) s[k] = *(const float2*)(ip + k * DD);

    const int t0 = c * L;
    const float2* xp = (const float2*)(X + (b * TT + t0) * DD) + d;
    float2* op = (float2*)(out + b * TOUT * DD) + d;

    constexpr int nb = L / U3;              // 8
    float2 x0[U3], x1[U3];
    #pragma unroll
    for (int u = 0; u < U3; ++u) x0[u] = xp[u * (DD/2)];

    int t = t0;
    #pragma unroll
    for (int ib = 0; ib < nb; ib += 2) {
        const float2* p1 = xp + (ib + 1) * U3 * (DD/2);
        #pragma unroll
        for (int u = 0; u < U3; ++u) x1[u] = p1[u * (DD/2)];
        #pragma unroll
        for (int u = 0; u < U3; ++u) {
            step_scan2(x0[u], wk, bk, s);
            if (t >= KK - 1) op[(t - (KK - 1)) * (DD/2)] = s[KK - 1];
            ++t;
        }
        if (ib + 2 < nb) {
            const float2* p2 = xp + (ib + 2) * U3 * (DD/2);
            #pragma unroll
            for (int u = 0; u < U3; ++u) x0[u] = p2[u * (DD/2)];
        }
        #pragma unroll
        for (int u = 0; u < U3; ++u) {
            step_scan2(x1[u], wk, bk, s);
            if (t >= KK - 1) op[(t - (KK - 1)) * (DD/2)] = s[KK - 1];
            ++t;
        }
    }
}
} // namespace

extern "C" void kernel_launch(void* const* d_in, const int* in_sizes, int n_in,
                              void* d_out, int out_size, void* d_ws, size_t ws_size,
                              hipStream_t stream)
{
    const float* X  = (const float*)d_in[0];
    const float* W  = (const float*)d_in[1];
    const float* Bv = (const float*)d_in[2];
    float* out = (float*)d_out;

    // ws need: sum 37.7 MB + infl 8.4 MB = 46.1 MB (round-3 proved ws >= ~98 MB)
    float* sum  = (float*)d_ws;
    float* infl = sum + (size_t)BB * C * NSUM * DD;

    pass1_summaries<<<BB * C, 256, 0, stream>>>(X, W, Bv, sum);
    pass2_inflows<<<BB * 4, 64, 0, stream>>>(sum, infl);
    pass3_scan<<<BB * C, 128, 0, stream>>>(X, W, Bv, infl, out);
}